// Round 6
// baseline (92.679 us; speedup 1.0000x reference)
//
#include <hip/hip_runtime.h>

// VectorQuantizer on MI355X — fused MFMA argmin + quantize + loss, v2.
// latents: [64, 64, 32, 32] f32, embedding: [512, 64] f32.
// d_out: quantized_st [64,64,32,32] f32 (4194304 elems) then vq_loss scalar f32.
// Math: quantized_st == embedding[argmin d2], vq_loss == 1.25 * mean((q - x)^2).
// Identity: per position, sum_d (q-x)^2 = (winning_score - 2) + ||x||^2,
// where winning_score = ||w||^2 + 2 - 2 x.w is the biased argmin score.

#define NUM_EMB 512
#define DIM 64
#define HW 1024
#define NPOS 65536
#define TOTAL 4194304
#define FUSED_BLOCKS 1024   // 64 positions per block, 16 per wave

typedef __attribute__((ext_vector_type(8))) short bf16x8;
typedef __attribute__((ext_vector_type(4))) float f32x4;

// d_ws layout:
//   [0, 65536)        : ushort wbf[512*64]   (bf16 bits of -2*W)
//   [65536, 67584)    : float  wwb[512]      (||w||^2 + 2.0 bias)
//   [67584, 198656)   : float  embT[64][512] (transposed embedding, f32 exact)
//   [198656, 202752)  : float  partial[1024]
//   [202752, 202756)  : uint   done_counter

__device__ __forceinline__ unsigned short f32_to_bf16_rne(float f) {
    unsigned int b = __builtin_bit_cast(unsigned int, f);
    return (unsigned short)((b + 0x7FFFu + ((b >> 16) & 1u)) >> 16);
}

__global__ __launch_bounds__(256) void prep_kernel(
    const float* __restrict__ emb, unsigned short* __restrict__ wbf,
    float* __restrict__ wwb, float* __restrict__ embT,
    unsigned int* __restrict__ done_counter) {
    const int t = blockIdx.x * 256 + threadIdx.x;  // 32768 threads
    if (t == 0) *done_counter = 0u;                // reset every launch
    if (t < NUM_EMB * DIM) {
        const float e = emb[t];
        wbf[t] = f32_to_bf16_rne(-2.0f * e);
        const int k = t >> 6, d = t & 63;
        embT[(d << 9) + k] = e;                    // transpose: embT[d][k]
    }
    if (t < NUM_EMB) {
        const float* row = emb + t * DIM;
        float s = 0.f;
#pragma unroll
        for (int i = 0; i < DIM; ++i) s = fmaf(row[i], row[i], s);
        wwb[t] = s + 2.0f;                         // +2 bias keeps packed scores positive
    }
}

// One wave = 16 consecutive positions. lane l: c=l&15 (position), g=l>>4 (k-group).
// acc[r] = ||w_k||^2 + 2 - 2 x.w_k for k = k0+g*4+r, pos = c.
// Packed argmin: u32 = (score_bits & ~511) | k; running min_u32; strict-min
// keeps the smallest k on masked-score ties (jnp.argmin tie-break).
__global__ __launch_bounds__(256) void fused_vq_kernel(
    const float* __restrict__ latents, const unsigned short* __restrict__ wbf,
    const float* __restrict__ wwb, const float* __restrict__ embT,
    float* __restrict__ out, float* __restrict__ partial,
    unsigned int* __restrict__ done_counter) {
    const int tid  = threadIdx.x;
    const int wave = tid >> 6;
    const int l    = tid & 63;
    const int c    = l & 15;
    const int g    = l >> 4;

    const int n0  = blockIdx.x * 64 + wave * 16;   // 16 positions, same b
    const int b   = n0 >> 10;
    const int hw0 = n0 & 1023;
    const float* xbase = latents + (size_t)b * (DIM * HW) + hw0 + c;

    // ---- load x once (nontemporal): bf16 frags + f32 ||x||^2 partial ----
    float x2 = 0.f;
    bf16x8 xf[2];
#pragma unroll
    for (int f = 0; f < 2; ++f) {
        const int d0 = f * 32 + g * 8;
        bf16x8 v;
#pragma unroll
        for (int j = 0; j < 8; ++j) {
            const float xv = __builtin_nontemporal_load(xbase + (d0 + j) * HW);
            x2 = fmaf(xv, xv, x2);
            v[j] = (short)f32_to_bf16_rne(xv);
        }
        xf[f] = v;
    }

    // ---- MFMA argmin over 512 codes, register double-buffered W stream ----
    const unsigned short* wp = wbf + c * DIM + g * 8;
    const float* wwp = wwb + g * 4;
    bf16x8 a0 = *(const bf16x8*)(wp);
    bf16x8 a1 = *(const bf16x8*)(wp + 32);
    f32x4  ww = *(const f32x4*)(wwp);
    unsigned int best = 0xFFFFFFFFu;

#pragma unroll 4
    for (int k0 = 0; k0 < NUM_EMB; k0 += 16) {
        // prefetch next tile unconditionally (last overreads into wwb/embT ws
        // region — valid memory, values unused)
        wp  += 16 * DIM;
        wwp += 16;
        bf16x8 na0 = *(const bf16x8*)(wp);
        bf16x8 na1 = *(const bf16x8*)(wp + 32);
        f32x4  nww = *(const f32x4*)(wwp);

        f32x4 acc = __builtin_amdgcn_mfma_f32_16x16x32_bf16(a0, xf[0], ww, 0, 0, 0);
        acc       = __builtin_amdgcn_mfma_f32_16x16x32_bf16(a1, xf[1], acc, 0, 0, 0);

        const unsigned int kb = (unsigned int)(k0 + g * 4);
        const unsigned int t0 = (__builtin_bit_cast(unsigned int, acc[0]) & 0xFFFFFE00u) | (kb + 0);
        const unsigned int t1 = (__builtin_bit_cast(unsigned int, acc[1]) & 0xFFFFFE00u) | (kb + 1);
        const unsigned int t2 = (__builtin_bit_cast(unsigned int, acc[2]) & 0xFFFFFE00u) | (kb + 2);
        const unsigned int t3 = (__builtin_bit_cast(unsigned int, acc[3]) & 0xFFFFFE00u) | (kb + 3);
        const unsigned int m01 = t0 < t1 ? t0 : t1;
        const unsigned int m23 = t2 < t3 ? t2 : t3;
        const unsigned int m   = m01 < m23 ? m01 : m23;
        best = m < best ? m : best;

        a0 = na0; a1 = na1; ww = nww;
    }

    // reduce over the 4 k-groups; afterwards all lanes of a position agree
    unsigned int o;
    o = __shfl_xor(best, 16); best = o < best ? o : best;
    o = __shfl_xor(best, 32); best = o < best ? o : best;

    // ---- loss partial: (score - 2) + ||x||^2, score replicated x4 ----
    const float s0 = __builtin_bit_cast(float, best & 0xFFFFFE00u);
    float contrib = x2 + 0.25f * (s0 - 2.0f);
#pragma unroll
    for (int off = 32; off; off >>= 1) contrib += __shfl_xor(contrib, off, 64);
    __shared__ float wsum[4];
    if (l == 0) wsum[wave] = contrib;

    // ---- write quantized output: lane l owns p4=(l&3)*4, d-rows (l>>2)+16i ----
    const int p4 = (l & 3) * 4;
    int k4[4];
#pragma unroll
    for (int i = 0; i < 4; ++i)
        k4[i] = (int)(__shfl(best, p4 + i) & 511u);
    const int drow = l >> 2;
    float* obase = out + (size_t)b * (DIM * HW) + hw0 + p4;
#pragma unroll
    for (int i = 0; i < 4; ++i) {
        const int d = i * 16 + drow;
        const float* er = embT + (d << 9);
        f32x4 q;
        q[0] = er[k4[0]]; q[1] = er[k4[1]]; q[2] = er[k4[2]]; q[3] = er[k4[3]];
        __builtin_nontemporal_store(q, (f32x4*)(obase + d * HW));
    }

    // ---- block partial + last-block finalize (no extra launch) ----
    __syncthreads();
    __shared__ int amlast;
    if (tid == 0) {
        partial[blockIdx.x] = (wsum[0] + wsum[1]) + (wsum[2] + wsum[3]);
        __threadfence();                            // publish partial
        const unsigned int old = atomicAdd(done_counter, 1u);
        amlast = (old == FUSED_BLOCKS - 1);
    }
    __syncthreads();
    if (amlast) {
        __threadfence();                            // see all partials
        double s = 0.0;
#pragma unroll
        for (int i = 0; i < FUSED_BLOCKS / 256; ++i)
            s += (double)partial[tid + i * 256];
#pragma unroll
        for (int off = 32; off; off >>= 1) s += __shfl_xor(s, off, 64);
        __shared__ double dsum[4];
        if ((tid & 63) == 0) dsum[tid >> 6] = s;
        __syncthreads();
        if (tid == 0) {
            const double tot = (dsum[0] + dsum[1]) + (dsum[2] + dsum[3]);
            out[TOTAL] = (float)(1.25 * tot / (double)TOTAL);
        }
    }
}

extern "C" void kernel_launch(void* const* d_in, const int* in_sizes, int n_in,
                              void* d_out, int out_size, void* d_ws, size_t ws_size,
                              hipStream_t stream) {
    const float* latents = (const float*)d_in[0];
    const float* emb     = (const float*)d_in[1];
    float* out = (float*)d_out;

    unsigned short* wbf     = (unsigned short*)d_ws;
    float*          wwb     = (float*)((char*)d_ws + 65536);
    float*          embT    = (float*)((char*)d_ws + 67584);
    float*          partial = (float*)((char*)d_ws + 198656);
    unsigned int*   done    = (unsigned int*)((char*)d_ws + 202752);

    prep_kernel<<<128, 256, 0, stream>>>(emb, wbf, wwb, embT, done);
    fused_vq_kernel<<<FUSED_BLOCKS, 256, 0, stream>>>(latents, wbf, wwb, embT,
                                                      out, partial, done);
}

// Round 7
// 57.260 us; speedup vs baseline: 1.6186x; 1.6186x over previous
//
#include <hip/hip_runtime.h>

// VectorQuantizer on MI355X — fused MFMA argmin + quantize + loss, v3.
// latents: [64, 64, 32, 32] f32, embedding: [512, 64] f32.
// d_out: quantized_st [64,64,32,32] f32 (4194304 elems) then vq_loss scalar f32.
// Math: quantized_st == embedding[argmin d2], vq_loss == 1.25 * mean((q - x)^2).
// Identity: per position, sum_d (q-x)^2 = (winning_score - 2) + ||x||^2,
// where winning_score = ||w||^2 + 2 - 2 x.w is the biased argmin score.
//
// Lesson from v2: NO __threadfence on gfx950 hot path (device fence =>
// per-XCD L2 writeback/invalidate, serializes all blocks), NO nontemporal
// hints on loads we want L2/L3-cached. Separate finalize launch is cheaper.

#define NUM_EMB 512
#define DIM 64
#define HW 1024
#define NPOS 65536
#define TOTAL 4194304
#define FUSED_BLOCKS 1024   // 64 positions per block, 16 per wave

typedef __attribute__((ext_vector_type(8))) short bf16x8;
typedef __attribute__((ext_vector_type(4))) float f32x4;

// d_ws layout:
//   [0, 65536)        : ushort wbf[512*64]   (bf16 bits of -2*W)
//   [65536, 67584)    : float  wwb[512]      (||w||^2 + 2.0 bias)
//   [67584, 198656)   : float  embT[64][512] (transposed embedding, f32 exact)
//   [198656, 202752)  : float  partial[1024]

__device__ __forceinline__ unsigned short f32_to_bf16_rne(float f) {
    unsigned int b = __builtin_bit_cast(unsigned int, f);
    return (unsigned short)((b + 0x7FFFu + ((b >> 16) & 1u)) >> 16);
}

__global__ __launch_bounds__(256) void prep_kernel(
    const float* __restrict__ emb, unsigned short* __restrict__ wbf,
    float* __restrict__ wwb, float* __restrict__ embT) {
    const int t = blockIdx.x * 256 + threadIdx.x;  // 32768 threads
    if (t < NUM_EMB * DIM) {
        const float e = emb[t];
        wbf[t] = f32_to_bf16_rne(-2.0f * e);
        const int k = t >> 6, d = t & 63;
        embT[(d << 9) + k] = e;                    // transpose: embT[d][k]
    }
    if (t < NUM_EMB) {
        const float* row = emb + t * DIM;
        float s = 0.f;
#pragma unroll
        for (int i = 0; i < DIM; ++i) s = fmaf(row[i], row[i], s);
        wwb[t] = s + 2.0f;                         // +2 bias keeps packed scores positive
    }
}

// One wave = 16 consecutive positions. lane l: c=l&15 (position), g=l>>4 (k-group).
// acc[r] = ||w_k||^2 + 2 - 2 x.w_k for k = k0+g*4+r, pos = c.
// Packed argmin: u32 = (score_bits & ~511) | k; running min_u32; strict-min
// keeps the smallest k on masked-score ties (jnp.argmin tie-break).
__global__ __launch_bounds__(256) void fused_vq_kernel(
    const float* __restrict__ latents, const unsigned short* __restrict__ wbf,
    const float* __restrict__ wwb, const float* __restrict__ embT,
    float* __restrict__ out, float* __restrict__ partial) {
    const int tid  = threadIdx.x;
    const int wave = tid >> 6;
    const int l    = tid & 63;
    const int c    = l & 15;
    const int g    = l >> 4;

    const int n0  = blockIdx.x * 64 + wave * 16;   // 16 positions, same b
    const int b   = n0 >> 10;
    const int hw0 = n0 & 1023;
    const float* xbase = latents + (size_t)b * (DIM * HW) + hw0 + c;

    // ---- load x once: bf16 frags + f32 ||x||^2 partial; fully coalesced ----
    float x2 = 0.f;
    bf16x8 xf[2];
#pragma unroll
    for (int f = 0; f < 2; ++f) {
        const int d0 = f * 32 + g * 8;
        bf16x8 v;
#pragma unroll
        for (int j = 0; j < 8; ++j) {
            const float xv = xbase[(d0 + j) * HW];
            x2 = fmaf(xv, xv, x2);
            v[j] = (short)f32_to_bf16_rne(xv);
        }
        xf[f] = v;
    }

    // ---- MFMA argmin over 512 codes, register double-buffered W stream ----
    const unsigned short* wp = wbf + c * DIM + g * 8;
    const float* wwp = wwb + g * 4;
    bf16x8 a0 = *(const bf16x8*)(wp);
    bf16x8 a1 = *(const bf16x8*)(wp + 32);
    f32x4  ww = *(const f32x4*)(wwp);
    unsigned int best = 0xFFFFFFFFu;

#pragma unroll 4
    for (int k0 = 0; k0 < NUM_EMB; k0 += 16) {
        // prefetch next tile unconditionally (last overreads into wwb/embT ws
        // region — valid memory, values unused)
        wp  += 16 * DIM;
        wwp += 16;
        bf16x8 na0 = *(const bf16x8*)(wp);
        bf16x8 na1 = *(const bf16x8*)(wp + 32);
        f32x4  nww = *(const f32x4*)(wwp);

        f32x4 acc = __builtin_amdgcn_mfma_f32_16x16x32_bf16(a0, xf[0], ww, 0, 0, 0);
        acc       = __builtin_amdgcn_mfma_f32_16x16x32_bf16(a1, xf[1], acc, 0, 0, 0);

        const unsigned int kb = (unsigned int)(k0 + g * 4);
        const unsigned int t0 = (__builtin_bit_cast(unsigned int, acc[0]) & 0xFFFFFE00u) | (kb + 0);
        const unsigned int t1 = (__builtin_bit_cast(unsigned int, acc[1]) & 0xFFFFFE00u) | (kb + 1);
        const unsigned int t2 = (__builtin_bit_cast(unsigned int, acc[2]) & 0xFFFFFE00u) | (kb + 2);
        const unsigned int t3 = (__builtin_bit_cast(unsigned int, acc[3]) & 0xFFFFFE00u) | (kb + 3);
        const unsigned int m01 = t0 < t1 ? t0 : t1;
        const unsigned int m23 = t2 < t3 ? t2 : t3;
        const unsigned int m   = m01 < m23 ? m01 : m23;
        best = m < best ? m : best;

        a0 = na0; a1 = na1; ww = nww;
    }

    // reduce over the 4 k-groups; afterwards all lanes of a position agree
    unsigned int o;
    o = __shfl_xor(best, 16); best = o < best ? o : best;
    o = __shfl_xor(best, 32); best = o < best ? o : best;

    // ---- loss partial: (score - 2) + ||x||^2, score replicated x4 ----
    const float s0 = __builtin_bit_cast(float, best & 0xFFFFFE00u);
    float contrib = x2 + 0.25f * (s0 - 2.0f);
#pragma unroll
    for (int off = 32; off; off >>= 1) contrib += __shfl_xor(contrib, off, 64);
    __shared__ float wsum[4];
    if (l == 0) wsum[wave] = contrib;

    // ---- write quantized output: lane l owns p4=(l&3)*4, d-rows (l>>2)+16i ----
    const int p4 = (l & 3) * 4;
    int k4[4];
#pragma unroll
    for (int i = 0; i < 4; ++i)
        k4[i] = (int)(__shfl(best, p4 + i) & 511u);
    const int drow = l >> 2;
    float* obase = out + (size_t)b * (DIM * HW) + hw0 + p4;
#pragma unroll
    for (int i = 0; i < 4; ++i) {
        const int d = i * 16 + drow;
        const float* er = embT + (d << 9);
        f32x4 q;
        q[0] = er[k4[0]]; q[1] = er[k4[1]]; q[2] = er[k4[2]]; q[3] = er[k4[3]];
        *(f32x4*)(obase + d * HW) = q;
    }

    __syncthreads();
    if (tid == 0)
        partial[blockIdx.x] = (wsum[0] + wsum[1]) + (wsum[2] + wsum[3]);
}

__global__ __launch_bounds__(256) void finalize_kernel(
    const float* __restrict__ partial, float* __restrict__ out) {
    double s = 0.0;
#pragma unroll
    for (int i = 0; i < FUSED_BLOCKS / 256; ++i)
        s += (double)partial[threadIdx.x + i * 256];
#pragma unroll
    for (int off = 32; off; off >>= 1) s += __shfl_xor(s, off, 64);
    __shared__ double dsum[4];
    if ((threadIdx.x & 63) == 0) dsum[threadIdx.x >> 6] = s;
    __syncthreads();
    if (threadIdx.x == 0) {
        const double tot = (dsum[0] + dsum[1]) + (dsum[2] + dsum[3]);
        out[TOTAL] = (float)(1.25 * tot / (double)TOTAL);
    }
}

extern "C" void kernel_launch(void* const* d_in, const int* in_sizes, int n_in,
                              void* d_out, int out_size, void* d_ws, size_t ws_size,
                              hipStream_t stream) {
    const float* latents = (const float*)d_in[0];
    const float* emb     = (const float*)d_in[1];
    float* out = (float*)d_out;

    unsigned short* wbf     = (unsigned short*)d_ws;
    float*          wwb     = (float*)((char*)d_ws + 65536);
    float*          embT    = (float*)((char*)d_ws + 67584);
    float*          partial = (float*)((char*)d_ws + 198656);

    prep_kernel<<<128, 256, 0, stream>>>(emb, wbf, wwb, embT);
    fused_vq_kernel<<<FUSED_BLOCKS, 256, 0, stream>>>(latents, wbf, wwb, embT,
                                                      out, partial);
    finalize_kernel<<<1, 256, 0, stream>>>(partial, out);
}

// Round 8
// 34.505 us; speedup vs baseline: 2.6860x; 1.6595x over previous
//
#include <hip/hip_runtime.h>

// VectorQuantizer on MI355X — fused MFMA argmin + quantize + loss, v4.
// latents: [64, 64, 32, 32] f32, embedding: [512, 64] f32.
// d_out: quantized_st [64,64,32,32] f32 (4194304 elems) then vq_loss scalar f32.
// Math: quantized_st == embedding[argmin d2], vq_loss == 1.25 * mean((q - x)^2).
// Identity: per position, sum_d (q-x)^2 = (winning_score - 2) + ||x||^2,
// where winning_score = ||w||^2 + 2 - 2 x.w is the biased argmin score.
//
// v4 structure lesson (rounds 4 vs 7 A/B): cost ~ wave_count x 64KB W-stream.
// -> 64 positions per wave (4 B-tiles in regs), 1024 single-wave blocks,
//    2-deep register prefetch of the W stream to cover L2 latency.

#define NUM_EMB 512
#define DIM 64
#define HW 1024
#define NPOS 65536
#define TOTAL 4194304
#define FUSED_BLOCKS 1024   // 64 threads (1 wave) per block, 64 positions each

typedef __attribute__((ext_vector_type(8))) short bf16x8;
typedef __attribute__((ext_vector_type(4))) float f32x4;

// d_ws layout:
//   [0, 65536)        : ushort wbf[512*64]   (bf16 bits of -2*W)
//   [65536, 67584)    : float  wwb[512]      (||w||^2 + 2.0 bias)
//   [67584, 198656)   : float  embT[64][512] (transposed embedding, f32 exact)
//   [198656, 202752)  : float  partial[1024]
// Prefetch overread (2 tiles past wbf end) lands in wwb/embT: valid memory.

__device__ __forceinline__ unsigned short f32_to_bf16_rne(float f) {
    unsigned int b = __builtin_bit_cast(unsigned int, f);
    return (unsigned short)((b + 0x7FFFu + ((b >> 16) & 1u)) >> 16);
}

__device__ __forceinline__ unsigned int umin(unsigned int a, unsigned int b) {
    return a < b ? a : b;
}

__global__ __launch_bounds__(256) void prep_kernel(
    const float* __restrict__ emb, unsigned short* __restrict__ wbf,
    float* __restrict__ wwb, float* __restrict__ embT) {
    const int t = blockIdx.x * 256 + threadIdx.x;  // 32768 threads
    if (t < NUM_EMB * DIM) {
        const float e = emb[t];
        wbf[t] = f32_to_bf16_rne(-2.0f * e);
        const int k = t >> 6, d = t & 63;
        embT[(d << 9) + k] = e;                    // transpose: embT[d][k]
    }
    if (t < NUM_EMB) {
        const float* row = emb + t * DIM;
        float s = 0.f;
#pragma unroll
        for (int i = 0; i < DIM; ++i) s = fmaf(row[i], row[i], s);
        wwb[t] = s + 2.0f;                         // +2 bias keeps packed scores positive
    }
}

// One wave = 64 consecutive positions = 4 MFMA B-tiles. lane l: c=l&15 (pos
// within tile), g=l>>4 (k-group / dim-block). Per 16-k tile and pos-tile t:
// acc[r] = ||w_k||^2 + 2 - 2 x.w_k for k = k0+g*4+r, pos = t*16+c.
// Packed argmin: u32 = (score_bits & ~511) | k; running min_u32; strict-min
// keeps the smallest k on masked-score ties (jnp.argmin tie-break).
__global__ __launch_bounds__(64) void fused_vq_kernel(
    const float* __restrict__ latents, const unsigned short* __restrict__ wbf,
    const float* __restrict__ wwb, const float* __restrict__ embT,
    float* __restrict__ out, float* __restrict__ partial) {
    const int l = threadIdx.x;                     // single wave
    const int c = l & 15;
    const int g = l >> 4;

    const int n0  = blockIdx.x * 64;               // 64 positions, same b row
    const int b   = n0 >> 10;
    const int hw0 = n0 & 1023;
    const float* xbase = latents + (size_t)b * (DIM * HW) + hw0 + c;

    // ---- load x once: 4 tiles x 2 K-halves of bf16 frags + f32 ||x||^2 ----
    float x2 = 0.f;
    bf16x8 xf[4][2];
#pragma unroll
    for (int t = 0; t < 4; ++t) {
#pragma unroll
        for (int f = 0; f < 2; ++f) {
            const int d0 = f * 32 + g * 8;
            bf16x8 v;
#pragma unroll
            for (int j = 0; j < 8; ++j) {
                const float xv = xbase[(d0 + j) * HW + t * 16];
                x2 = fmaf(xv, xv, x2);
                v[j] = (short)f32_to_bf16_rne(xv);
            }
            xf[t][f] = v;
        }
    }

    // ---- MFMA argmin over 512 codes; 4-slot rotating W buffer, 2-deep ----
    const unsigned short* wbase = wbf + c * DIM + g * 8;   // +it*1024 per tile
    const float* wwbase = wwb + g * 4;                     // +it*16 per tile

    bf16x8 abuf[4][2];
    f32x4  wwbuf[4];
#pragma unroll
    for (int i = 0; i < 2; ++i) {
        abuf[i][0] = *(const bf16x8*)(wbase + i * 1024);
        abuf[i][1] = *(const bf16x8*)(wbase + i * 1024 + 32);
        wwbuf[i]   = *(const f32x4*)(wwbase + i * 16);
    }

    unsigned int best[4] = {0xFFFFFFFFu, 0xFFFFFFFFu, 0xFFFFFFFFu, 0xFFFFFFFFu};

#pragma unroll 4
    for (int it = 0; it < 32; ++it) {
        const int bi = it & 3;
        const int pi = (it + 2) & 3;
        // prefetch tile it+2 (it=30,31 overread into wwb/embT: valid, unused)
        abuf[pi][0] = *(const bf16x8*)(wbase + (it + 2) * 1024);
        abuf[pi][1] = *(const bf16x8*)(wbase + (it + 2) * 1024 + 32);
        wwbuf[pi]   = *(const f32x4*)(wwbase + (it + 2) * 16);

        const unsigned int kb = (unsigned int)(it * 16 + g * 4);
#pragma unroll
        for (int t = 0; t < 4; ++t) {
            f32x4 acc = __builtin_amdgcn_mfma_f32_16x16x32_bf16(abuf[bi][0], xf[t][0], wwbuf[bi], 0, 0, 0);
            acc       = __builtin_amdgcn_mfma_f32_16x16x32_bf16(abuf[bi][1], xf[t][1], acc, 0, 0, 0);
            // v_and_or_b32 + v_min3_u32-friendly forms
            const unsigned int t0 = (__builtin_bit_cast(unsigned int, acc[0]) & 0xFFFFFE00u) | (kb + 0);
            const unsigned int t1 = (__builtin_bit_cast(unsigned int, acc[1]) & 0xFFFFFE00u) | (kb + 1);
            const unsigned int t2 = (__builtin_bit_cast(unsigned int, acc[2]) & 0xFFFFFE00u) | (kb + 2);
            const unsigned int t3 = (__builtin_bit_cast(unsigned int, acc[3]) & 0xFFFFFE00u) | (kb + 3);
            best[t] = umin(umin(umin(t0, t1), umin(t2, t3)), best[t]);
        }
    }

    // reduce each tile's best over the 4 k-groups (lanes c, c+16, c+32, c+48)
#pragma unroll
    for (int t = 0; t < 4; ++t) {
        unsigned int o;
        o = __shfl_xor(best[t], 16); best[t] = umin(best[t], o);
        o = __shfl_xor(best[t], 32); best[t] = umin(best[t], o);
    }

    // ---- loss partial: (score - 2) + ||x||^2, scores replicated x4 over g ----
    float ssum = 0.f;
#pragma unroll
    for (int t = 0; t < 4; ++t)
        ssum += __builtin_bit_cast(float, best[t] & 0xFFFFFE00u) - 2.0f;
    float contrib = x2 + 0.25f * ssum;
#pragma unroll
    for (int off = 32; off; off >>= 1) contrib += __shfl_xor(contrib, off, 64);
    if (l == 0) partial[blockIdx.x] = contrib;

    // ---- write quantized output: per tile, lane l owns p4=(l&3)*4,
    //      d-rows (l>>2)+16i; gather L1-hot embT rows ----
    const int p4   = (l & 3) * 4;
    const int drow = l >> 2;
#pragma unroll
    for (int t = 0; t < 4; ++t) {
        int k4[4];
#pragma unroll
        for (int i = 0; i < 4; ++i)
            k4[i] = (int)(__shfl(best[t], p4 + i) & 511u);
        float* obase = out + (size_t)b * (DIM * HW) + hw0 + t * 16 + p4;
#pragma unroll
        for (int i = 0; i < 4; ++i) {
            const int d = i * 16 + drow;
            const float* er = embT + (d << 9);
            f32x4 q;
            q[0] = er[k4[0]]; q[1] = er[k4[1]]; q[2] = er[k4[2]]; q[3] = er[k4[3]];
            *(f32x4*)(obase + d * HW) = q;
        }
    }
}

__global__ __launch_bounds__(256) void finalize_kernel(
    const float* __restrict__ partial, float* __restrict__ out) {
    double s = 0.0;
#pragma unroll
    for (int i = 0; i < FUSED_BLOCKS / 256; ++i)
        s += (double)partial[threadIdx.x + i * 256];
#pragma unroll
    for (int off = 32; off; off >>= 1) s += __shfl_xor(s, off, 64);
    __shared__ double dsum[4];
    if ((threadIdx.x & 63) == 0) dsum[threadIdx.x >> 6] = s;
    __syncthreads();
    if (threadIdx.x == 0) {
        const double tot = (dsum[0] + dsum[1]) + (dsum[2] + dsum[3]);
        out[TOTAL] = (float)(1.25 * tot / (double)TOTAL);
    }
}

extern "C" void kernel_launch(void* const* d_in, const int* in_sizes, int n_in,
                              void* d_out, int out_size, void* d_ws, size_t ws_size,
                              hipStream_t stream) {
    const float* latents = (const float*)d_in[0];
    const float* emb     = (const float*)d_in[1];
    float* out = (float*)d_out;

    unsigned short* wbf     = (unsigned short*)d_ws;
    float*          wwb     = (float*)((char*)d_ws + 65536);
    float*          embT    = (float*)((char*)d_ws + 67584);
    float*          partial = (float*)((char*)d_ws + 198656);

    prep_kernel<<<128, 256, 0, stream>>>(emb, wbf, wwb, embT);
    fused_vq_kernel<<<FUSED_BLOCKS, 64, 0, stream>>>(latents, wbf, wwb, embT,
                                                     out, partial);
    finalize_kernel<<<1, 256, 0, stream>>>(partial, out);
}

// Round 9
// 29.355 us; speedup vs baseline: 3.1572x; 1.1754x over previous
//
#include <hip/hip_runtime.h>

// VectorQuantizer on MI355X — fused MFMA argmin + quantize + loss, v5.
// latents: [64, 64, 32, 32] f32, embedding: [512, 64] f32.
// d_out: quantized_st [64,64,32,32] f32 (4194304 elems) then vq_loss scalar f32.
// Math: quantized_st == embedding[argmin d2], vq_loss == 1.25 * mean((q - x)^2).
// Identity: per position, sum_d (q-x)^2 = (winning_score - 2) + ||x||^2.
//
// v5 lesson chain: r4/r7/r8 A/B => cost ~ per-wave W-stream served from L2/L3
// (latency-bound, L1 too small). Fix: codebook in LDS (66 KB/block), XOR-
// swizzled (byte ^= (row&7)<<4) to kill the 128B-stride bank conflict.

#define NUM_EMB 512
#define DIM 64
#define HW 1024
#define NPOS 65536
#define TOTAL 4194304
#define FUSED_BLOCKS 512    // 256 threads = 4 waves; 128 positions per block

typedef __attribute__((ext_vector_type(8))) short bf16x8;
typedef __attribute__((ext_vector_type(4))) float f32x4;

// d_ws layout:
//   [0, 65536)        : ushort wbf[512*64]   (bf16 bits of -2*W)
//   [65536, 67584)    : float  wwb[512]      (||w||^2 + 2.0 bias)
//   [67584, 198656)   : float  embT[64][512] (transposed embedding, f32 exact)
//   [198656, 200704)  : float  partial[512]

__device__ __forceinline__ unsigned short f32_to_bf16_rne(float f) {
    unsigned int b = __builtin_bit_cast(unsigned int, f);
    return (unsigned short)((b + 0x7FFFu + ((b >> 16) & 1u)) >> 16);
}

__device__ __forceinline__ unsigned int umin32(unsigned int a, unsigned int b) {
    return a < b ? a : b;
}

__global__ __launch_bounds__(256) void prep_kernel(
    const float* __restrict__ emb, unsigned short* __restrict__ wbf,
    float* __restrict__ wwb, float* __restrict__ embT) {
    const int t = blockIdx.x * 256 + threadIdx.x;  // 32768 threads
    if (t < NUM_EMB * DIM) {
        const float e = emb[t];
        wbf[t] = f32_to_bf16_rne(-2.0f * e);
        const int k = t >> 6, d = t & 63;
        embT[(d << 9) + k] = e;                    // transpose: embT[d][k]
    }
    if (t < NUM_EMB) {
        const float* row = emb + t * DIM;
        float s = 0.f;
#pragma unroll
        for (int i = 0; i < DIM; ++i) s = fmaf(row[i], row[i], s);
        wwb[t] = s + 2.0f;                         // +2 bias keeps packed scores positive
    }
}

// Block: 4 waves x 32 positions. Wave lane l: c=l&15 (position in tile),
// g=l>>4 (k-group / dim-block). Codebook staged in LDS, XOR-swizzled:
// 16B chunk ch of row r stored at chunk ch^(r&7). k-tile rows are it*16+c,
// so the swizzle term g^(c&7) is loop-invariant; a1 chunk = a0 chunk ^ 4.
// acc[r] = ||w_k||^2 + 2 - 2 x.w_k for k = k0+g*4+r, pos = t*16+c.
// Packed argmin: u32 = (score_bits & ~511) | k; running min_u32; strict-min
// keeps the smallest k on masked-score ties (jnp.argmin tie-break).
__global__ __launch_bounds__(256) void fused_vq_kernel(
    const float* __restrict__ latents, const unsigned short* __restrict__ wbf,
    const float* __restrict__ wwb, const float* __restrict__ embT,
    float* __restrict__ out, float* __restrict__ partial) {
    extern __shared__ char smem[];                 // 66560 B dynamic
    f32x4* wl16 = (f32x4*)smem;                    // 4096 x 16B (swizzled wbf)
    float* wwl  = (float*)(smem + 65536);          // 512 floats

    const int tid  = threadIdx.x;
    const int wave = tid >> 6;
    const int l    = tid & 63;
    const int c    = l & 15;
    const int g    = l >> 4;

    // ---- stage codebook into LDS (coalesced 16B, swizzled dest) ----
    const f32x4* wg = (const f32x4*)wbf;           // 4096 chunks of 16B
#pragma unroll
    for (int r = 0; r < 16; ++r) {
        const int idx = r * 256 + tid;
        const int sw  = (idx & ~7) | ((idx ^ (idx >> 3)) & 7);  // ch ^ (row&7)
        wl16[sw] = wg[idx];
    }
    if (tid < 128) ((f32x4*)wwl)[tid] = ((const f32x4*)wwb)[tid];

    const int n0  = blockIdx.x * 128 + wave * 32;  // 32 positions, same b
    const int b   = n0 >> 10;
    const int hw0 = n0 & 1023;
    const float* xbase = latents + (size_t)b * (DIM * HW) + hw0 + c;

    // ---- load x once: 2 tiles x 2 K-halves bf16 frags + f32 ||x||^2 ----
    float x2 = 0.f;
    bf16x8 xf[2][2];
#pragma unroll
    for (int t = 0; t < 2; ++t) {
#pragma unroll
        for (int f = 0; f < 2; ++f) {
            const int d0 = f * 32 + g * 8;
            bf16x8 v;
#pragma unroll
            for (int j = 0; j < 8; ++j) {
                const float xv = xbase[(d0 + j) * HW + t * 16];
                x2 = fmaf(xv, xv, x2);
                v[j] = (short)f32_to_bf16_rne(xv);
            }
            xf[t][f] = v;
        }
    }
    __syncthreads();                               // LDS codebook ready

    // ---- MFMA argmin over 512 codes from LDS ----
    const char* arow = smem + c * 128 + ((g ^ (c & 7)) << 4);  // a0 addr base
    unsigned int best[2] = {0xFFFFFFFFu, 0xFFFFFFFFu};

#pragma unroll 4
    for (int it = 0; it < 32; ++it) {
        const bf16x8 a0 = *(const bf16x8*)(arow + it * 2048);
        const bf16x8 a1 = *(const bf16x8*)((const char*)arow + (it * 2048) + ((((g ^ (c & 7)) << 4) ^ 64) - ((g ^ (c & 7)) << 4)));
        const f32x4  ww4 = *(const f32x4*)(wwl + it * 16 + g * 4);

        const unsigned int kb = (unsigned int)(it * 16 + g * 4);
#pragma unroll
        for (int t = 0; t < 2; ++t) {
            f32x4 acc = __builtin_amdgcn_mfma_f32_16x16x32_bf16(a0, xf[t][0], ww4, 0, 0, 0);
            acc       = __builtin_amdgcn_mfma_f32_16x16x32_bf16(a1, xf[t][1], acc, 0, 0, 0);
            const unsigned int t0 = (__builtin_bit_cast(unsigned int, acc[0]) & 0xFFFFFE00u) | (kb + 0);
            const unsigned int t1 = (__builtin_bit_cast(unsigned int, acc[1]) & 0xFFFFFE00u) | (kb + 1);
            const unsigned int t2 = (__builtin_bit_cast(unsigned int, acc[2]) & 0xFFFFFE00u) | (kb + 2);
            const unsigned int t3 = (__builtin_bit_cast(unsigned int, acc[3]) & 0xFFFFFE00u) | (kb + 3);
            best[t] = umin32(umin32(umin32(t0, t1), umin32(t2, t3)), best[t]);
        }
    }

    // reduce over the 4 k-groups (lanes c, c+16, c+32, c+48)
#pragma unroll
    for (int t = 0; t < 2; ++t) {
        unsigned int o;
        o = __shfl_xor(best[t], 16); best[t] = umin32(best[t], o);
        o = __shfl_xor(best[t], 32); best[t] = umin32(best[t], o);
    }

    // ---- loss partial: (score - 2) + ||x||^2, scores replicated x4 over g ----
    float ssum = 0.f;
#pragma unroll
    for (int t = 0; t < 2; ++t)
        ssum += __builtin_bit_cast(float, best[t] & 0xFFFFFE00u) - 2.0f;
    float contrib = x2 + 0.25f * ssum;
#pragma unroll
    for (int off = 32; off; off >>= 1) contrib += __shfl_xor(contrib, off, 64);
    __shared__ float wsum[4];
    if (l == 0) wsum[wave] = contrib;

    // ---- write quantized output: per tile, lane owns p4=(l&3)*4 positions,
    //      d-rows (l>>2)+16i; gather embT rows (128 KB, L1/L2-hot) ----
    const int p4   = (l & 3) * 4;
    const int drow = l >> 2;
#pragma unroll
    for (int t = 0; t < 2; ++t) {
        int k4[4];
#pragma unroll
        for (int i = 0; i < 4; ++i)
            k4[i] = (int)(__shfl(best[t], p4 + i) & 511u);
        float* obase = out + (size_t)b * (DIM * HW) + hw0 + t * 16 + p4;
#pragma unroll
        for (int i = 0; i < 4; ++i) {
            const int d = i * 16 + drow;
            const float* er = embT + (d << 9);
            f32x4 q;
            q[0] = er[k4[0]]; q[1] = er[k4[1]]; q[2] = er[k4[2]]; q[3] = er[k4[3]];
            *(f32x4*)(obase + d * HW) = q;
        }
    }

    __syncthreads();
    if (tid == 0)
        partial[blockIdx.x] = (wsum[0] + wsum[1]) + (wsum[2] + wsum[3]);
}

__global__ __launch_bounds__(256) void finalize_kernel(
    const float* __restrict__ partial, float* __restrict__ out) {
    double s = 0.0;
#pragma unroll
    for (int i = 0; i < FUSED_BLOCKS / 256; ++i)
        s += (double)partial[threadIdx.x + i * 256];
#pragma unroll
    for (int off = 32; off; off >>= 1) s += __shfl_xor(s, off, 64);
    __shared__ double dsum[4];
    if ((threadIdx.x & 63) == 0) dsum[threadIdx.x >> 6] = s;
    __syncthreads();
    if (threadIdx.x == 0) {
        const double tot = (dsum[0] + dsum[1]) + (dsum[2] + dsum[3]);
        out[TOTAL] = (float)(1.25 * tot / (double)TOTAL);
    }
}

extern "C" void kernel_launch(void* const* d_in, const int* in_sizes, int n_in,
                              void* d_out, int out_size, void* d_ws, size_t ws_size,
                              hipStream_t stream) {
    const float* latents = (const float*)d_in[0];
    const float* emb     = (const float*)d_in[1];
    float* out = (float*)d_out;

    unsigned short* wbf     = (unsigned short*)d_ws;
    float*          wwb     = (float*)((char*)d_ws + 65536);
    float*          embT    = (float*)((char*)d_ws + 67584);
    float*          partial = (float*)((char*)d_ws + 198656);

    static bool attr_done = false;
    if (!attr_done) {
        (void)hipFuncSetAttribute((const void*)fused_vq_kernel,
                                  hipFuncAttributeMaxDynamicSharedMemorySize, 66560);
        attr_done = true;
    }

    prep_kernel<<<128, 256, 0, stream>>>(emb, wbf, wwb, embT);
    fused_vq_kernel<<<FUSED_BLOCKS, 256, 66560, stream>>>(latents, wbf, wwb, embT,
                                                          out, partial);
    finalize_kernel<<<1, 256, 0, stream>>>(partial, out);
}

// Round 10
// 28.822 us; speedup vs baseline: 3.2156x; 1.0185x over previous
//
#include <hip/hip_runtime.h>

// VectorQuantizer on MI355X — fused MFMA argmin + quantize + loss, v6.
// latents: [64, 64, 32, 32] f32, embedding: [512, 64] f32.
// d_out: quantized_st [64,64,32,32] f32 (4194304 elems) then vq_loss scalar f32.
// Math: quantized_st == embedding[argmin d2], vq_loss == 1.25 * mean((q - x)^2).
// Identity: per position, sum_d (q-x)^2 = (winning_score - 2) + ||x||^2.
//
// v6: two kernels only. Codebook lives in LDS (XOR-swizzled); output is
// gathered from the SAME LDS codebook (q = -0.5 * bf16(-2w), err ~4e-6);
// loss accumulated via one f32 atomic per block into out[TOTAL] (zeroed by
// prep). Lessons kept: no __threadfence, no nontemporal, LDS (not L2) serves
// the per-wave 64KB codebook stream.

#define NUM_EMB 512
#define DIM 64
#define HW 1024
#define TOTAL 4194304
#define FUSED_BLOCKS 512    // 256 threads = 4 waves; 128 positions per block

typedef __attribute__((ext_vector_type(8))) short bf16x8;
typedef __attribute__((ext_vector_type(4))) float f32x4;

// d_ws layout:
//   [0, 65536)        : ushort wbf[512*64]   (bf16 bits of -2*W)
//   [65536, 67584)    : float  wwb[512]      (||w||^2 + 2.0 bias)

__device__ __forceinline__ unsigned short f32_to_bf16_rne(float f) {
    unsigned int b = __builtin_bit_cast(unsigned int, f);
    return (unsigned short)((b + 0x7FFFu + ((b >> 16) & 1u)) >> 16);
}

__device__ __forceinline__ unsigned int umin32(unsigned int a, unsigned int b) {
    return a < b ? a : b;
}

__global__ __launch_bounds__(256) void prep_kernel(
    const float* __restrict__ emb, unsigned short* __restrict__ wbf,
    float* __restrict__ wwb, float* __restrict__ out) {
    const int t = blockIdx.x * 256 + threadIdx.x;  // 32768 threads
    if (t == 0) out[TOTAL] = 0.f;                  // loss accumulator (poisoned otherwise)
    if (t < NUM_EMB * DIM) wbf[t] = f32_to_bf16_rne(-2.0f * emb[t]);
    if (t < NUM_EMB) {
        const float* row = emb + t * DIM;
        float s = 0.f;
#pragma unroll
        for (int i = 0; i < DIM; ++i) s = fmaf(row[i], row[i], s);
        wwb[t] = s + 2.0f;                         // +2 bias keeps packed scores positive
    }
}

// Block: 4 waves x 32 positions. Wave lane l: c=l&15 (position in tile),
// g=l>>4 (k-group / dim-block). Codebook staged in LDS, XOR-swizzled:
// 16B chunk ch of row k stored at chunk ch^(k&7); k-tile rows are it*16+c,
// so the per-lane swizzle g^(c&7) is loop-invariant (a1 chunk = a0 ^ 4).
// acc[r] = ||w_k||^2 + 2 - 2 x.w_k for k = k0+g*4+r, pos = t*16+c.
// Packed argmin: u32 = (score_bits & ~511) | k; running min_u32; strict-min
// keeps the smallest k on masked-score ties (jnp.argmin tie-break).
__global__ __launch_bounds__(256) void fused_vq_kernel(
    const float* __restrict__ latents, const unsigned short* __restrict__ wbf,
    const float* __restrict__ wwb, float* __restrict__ out) {
    extern __shared__ char smem[];                 // 66560 B dynamic
    f32x4* wl16 = (f32x4*)smem;                    // 4096 x 16B (swizzled wbf)
    float* wwl  = (float*)(smem + 65536);          // 512 floats

    const int tid  = threadIdx.x;
    const int wave = tid >> 6;
    const int l    = tid & 63;
    const int c    = l & 15;
    const int g    = l >> 4;

    const int n0  = blockIdx.x * 128 + wave * 32;  // 32 positions, same b
    const int b   = n0 >> 10;
    const int hw0 = n0 & 1023;
    const float* xbase = latents + (size_t)b * (DIM * HW) + hw0 + c;

    // ---- x loads FIRST (HBM latency hides under L3 staging below) ----
    float x2 = 0.f;
    bf16x8 xf[2][2];
#pragma unroll
    for (int t = 0; t < 2; ++t) {
#pragma unroll
        for (int f = 0; f < 2; ++f) {
            const int d0 = f * 32 + g * 8;
            bf16x8 v;
#pragma unroll
            for (int j = 0; j < 8; ++j) {
                const float xv = xbase[(d0 + j) * HW + t * 16];
                x2 = fmaf(xv, xv, x2);
                v[j] = (short)f32_to_bf16_rne(xv);
            }
            xf[t][f] = v;
        }
    }

    // ---- stage codebook into LDS (coalesced 16B, swizzled dest) ----
    const f32x4* wg = (const f32x4*)wbf;           // 4096 chunks of 16B
#pragma unroll
    for (int r = 0; r < 16; ++r) {
        const int idx = r * 256 + tid;
        const int sw  = (idx & ~7) | ((idx ^ (idx >> 3)) & 7);  // ch ^ (row&7)
        wl16[sw] = wg[idx];
    }
    if (tid < 128) ((f32x4*)wwl)[tid] = ((const f32x4*)wwb)[tid];
    __syncthreads();                               // LDS codebook ready

    // ---- MFMA argmin over 512 codes from LDS ----
    const int   sw0  = (g ^ (c & 7)) << 4;         // loop-invariant swizzle
    const char* arow = smem + c * 128;
    unsigned int best[2] = {0xFFFFFFFFu, 0xFFFFFFFFu};

#pragma unroll 4
    for (int it = 0; it < 32; ++it) {
        const bf16x8 a0  = *(const bf16x8*)(arow + it * 2048 + sw0);
        const bf16x8 a1  = *(const bf16x8*)(arow + it * 2048 + (sw0 ^ 64));
        const f32x4  ww4 = *(const f32x4*)(wwl + it * 16 + g * 4);

        const unsigned int kb = (unsigned int)(it * 16 + g * 4);
#pragma unroll
        for (int t = 0; t < 2; ++t) {
            f32x4 acc = __builtin_amdgcn_mfma_f32_16x16x32_bf16(a0, xf[t][0], ww4, 0, 0, 0);
            acc       = __builtin_amdgcn_mfma_f32_16x16x32_bf16(a1, xf[t][1], acc, 0, 0, 0);
            const unsigned int t0 = (__builtin_bit_cast(unsigned int, acc[0]) & 0xFFFFFE00u) | (kb + 0);
            const unsigned int t1 = (__builtin_bit_cast(unsigned int, acc[1]) & 0xFFFFFE00u) | (kb + 1);
            const unsigned int t2 = (__builtin_bit_cast(unsigned int, acc[2]) & 0xFFFFFE00u) | (kb + 2);
            const unsigned int t3 = (__builtin_bit_cast(unsigned int, acc[3]) & 0xFFFFFE00u) | (kb + 3);
            best[t] = umin32(umin32(umin32(t0, t1), umin32(t2, t3)), best[t]);
        }
    }

    // reduce over the 4 k-groups (lanes c, c+16, c+32, c+48)
#pragma unroll
    for (int t = 0; t < 2; ++t) {
        unsigned int o;
        o = __shfl_xor(best[t], 16); best[t] = umin32(best[t], o);
        o = __shfl_xor(best[t], 32); best[t] = umin32(best[t], o);
    }

    // ---- loss partial: (score - 2) + ||x||^2, scores replicated x4 over g ----
    float ssum = 0.f;
#pragma unroll
    for (int t = 0; t < 2; ++t)
        ssum += __builtin_bit_cast(float, best[t] & 0xFFFFFE00u) - 2.0f;
    float contrib = x2 + 0.25f * ssum;
#pragma unroll
    for (int off = 32; off; off >>= 1) contrib += __shfl_xor(contrib, off, 64);
    __shared__ float wsum[4];
    if (l == 0) wsum[wave] = contrib;

    // ---- write quantized output gathered from the LDS codebook ----
    // q = -0.5 * bf16(-2w): exact *0.5, only bf16(w) rounding (~4e-6).
    // 16 lanes share k (2-way bank aliasing only — free per m136).
    const int p4   = (l & 3) * 4;
    const int drow = l >> 2;
#pragma unroll
    for (int t = 0; t < 2; ++t) {
        int k4[4];
#pragma unroll
        for (int j = 0; j < 4; ++j)
            k4[j] = (int)(__shfl(best[t], p4 + j) & 511u);
        float* obase = out + (size_t)b * (DIM * HW) + hw0 + t * 16 + p4;
#pragma unroll
        for (int i = 0; i < 4; ++i) {
            const int d = i * 16 + drow;
            f32x4 q;
#pragma unroll
            for (int j = 0; j < 4; ++j) {
                const int k = k4[j];
                const int byte = k * 128 + ((((d >> 3) ^ (k & 7))) << 4) + ((d & 7) << 1);
                const unsigned short wv = *(const unsigned short*)(smem + byte);
                q[j] = -0.5f * __builtin_bit_cast(float, (unsigned int)wv << 16);
            }
            *(f32x4*)(obase + d * HW) = q;
        }
    }

    // ---- one f32 atomic per block; adds stagger with block completion ----
    __syncthreads();
    if (tid == 0) {
        const float tot = (wsum[0] + wsum[1]) + (wsum[2] + wsum[3]);
        atomicAdd(out + TOTAL, tot * (1.25f / (float)TOTAL));
    }
}

extern "C" void kernel_launch(void* const* d_in, const int* in_sizes, int n_in,
                              void* d_out, int out_size, void* d_ws, size_t ws_size,
                              hipStream_t stream) {
    const float* latents = (const float*)d_in[0];
    const float* emb     = (const float*)d_in[1];
    float* out = (float*)d_out;

    unsigned short* wbf = (unsigned short*)d_ws;
    float*          wwb = (float*)((char*)d_ws + 65536);

    static bool attr_done = false;
    if (!attr_done) {
        (void)hipFuncSetAttribute((const void*)fused_vq_kernel,
                                  hipFuncAttributeMaxDynamicSharedMemorySize, 66560);
        attr_done = true;
    }

    prep_kernel<<<128, 256, 0, stream>>>(emb, wbf, wwb, out);
    fused_vq_kernel<<<FUSED_BLOCKS, 256, 66560, stream>>>(latents, wbf, wwb, out);
}

// Round 11
// 27.153 us; speedup vs baseline: 3.4132x; 1.0614x over previous
//
#include <hip/hip_runtime.h>

// VectorQuantizer on MI355X — fused MFMA argmin + quantize + loss, v7.
// latents: [64, 64, 32, 32] f32, embedding: [512, 64] f32.
// d_out: quantized_st [64,64,32,32] f32 (4194304 elems) then vq_loss scalar f32.
// Math: quantized_st == embedding[argmin d2], vq_loss == 1.25 * mean((q - x)^2).
// Identity: sum over block positions of (q-x)^2 =
//   sum_pos (winning_score - 2) + sum_all_elems x^2   (score = ||w||^2+2-2x.w).
//
// v7 vs v6: (a) x-loads and staging loads issued as full static batches into
// register arrays (one exposed L3 latency, not ~8); (b) loss atomic moved
// before the output stores, no trailing __syncthreads (store drain at endpgm);
// (c) __launch_bounds__(256,2) for the larger register budget.
// Kept: LDS codebook (XOR-swizzled), output gathered from LDS bf16 codebook,
// no __threadfence, no nontemporal.

#define NUM_EMB 512
#define DIM 64
#define HW 1024
#define TOTAL 4194304
#define FUSED_BLOCKS 512    // 256 threads = 4 waves; 128 positions per block

typedef __attribute__((ext_vector_type(8))) short bf16x8;
typedef __attribute__((ext_vector_type(4))) float f32x4;

// d_ws layout:
//   [0, 65536)        : ushort wbf[512*64]   (bf16 bits of -2*W)
//   [65536, 67584)    : float  wwb[512]      (||w||^2 + 2.0 bias)

__device__ __forceinline__ unsigned short f32_to_bf16_rne(float f) {
    unsigned int b = __builtin_bit_cast(unsigned int, f);
    return (unsigned short)((b + 0x7FFFu + ((b >> 16) & 1u)) >> 16);
}

__device__ __forceinline__ unsigned int umin32(unsigned int a, unsigned int b) {
    return a < b ? a : b;
}

__global__ __launch_bounds__(256) void prep_kernel(
    const float* __restrict__ emb, unsigned short* __restrict__ wbf,
    float* __restrict__ wwb, float* __restrict__ out) {
    const int t = blockIdx.x * 256 + threadIdx.x;  // 32768 threads
    if (t == 0) out[TOTAL] = 0.f;                  // loss accumulator
    if (t < NUM_EMB * DIM) wbf[t] = f32_to_bf16_rne(-2.0f * emb[t]);
    if (t < NUM_EMB) {
        const float* row = emb + t * DIM;
        float s = 0.f;
#pragma unroll
        for (int i = 0; i < DIM; ++i) s = fmaf(row[i], row[i], s);
        wwb[t] = s + 2.0f;                         // +2 bias keeps packed scores positive
    }
}

// Block: 4 waves x 32 positions. Wave lane l: c=l&15 (position in tile),
// g=l>>4 (k-group / dim-block). Codebook staged in LDS, XOR-swizzled:
// 16B chunk ch of row k stored at chunk ch^(k&7); k-tile rows are it*16+c,
// so the per-lane swizzle g^(c&7) is loop-invariant (a1 chunk = a0 ^ 4).
// acc[r] = ||w_k||^2 + 2 - 2 x.w_k for k = k0+g*4+r, pos = t*16+c.
// Packed argmin: u32 = (score_bits & ~511) | k; running min_u32; strict-min
// keeps the smallest k on masked-score ties (jnp.argmin tie-break).
__global__ __launch_bounds__(256, 2) void fused_vq_kernel(
    const float* __restrict__ latents, const unsigned short* __restrict__ wbf,
    const float* __restrict__ wwb, float* __restrict__ out) {
    extern __shared__ char smem[];                 // 66560 B dynamic
    f32x4* wl16 = (f32x4*)smem;                    // 4096 x 16B (swizzled wbf)
    float* wwl  = (float*)(smem + 65536);          // 512 floats

    const int tid  = threadIdx.x;
    const int wave = tid >> 6;
    const int l    = tid & 63;
    const int c    = l & 15;
    const int g    = l >> 4;

    const int n0  = blockIdx.x * 128 + wave * 32;  // 32 positions, same b
    const int b   = n0 >> 10;
    const int hw0 = n0 & 1023;
    const float* xbase = latents + (size_t)b * (DIM * HW) + hw0 + c;

    // ---- PHASE A: issue ALL 32 x-loads (static reg array => one batch) ----
    float xr[32];
#pragma unroll
    for (int t = 0; t < 2; ++t)
#pragma unroll
        for (int f = 0; f < 2; ++f)
#pragma unroll
            for (int j = 0; j < 8; ++j)
                xr[t * 16 + f * 8 + j] = xbase[(f * 32 + g * 8 + j) * HW + t * 16];

    // ---- PHASE B: issue ALL staging loads (16 f32x4 + ww) as a batch ----
    const f32x4* wg = (const f32x4*)wbf;           // 4096 chunks of 16B
    f32x4 sr[16];
#pragma unroll
    for (int r = 0; r < 16; ++r) sr[r] = wg[r * 256 + tid];
    f32x4 wws;
    if (tid < 128) wws = ((const f32x4*)wwb)[tid];

    // ---- PHASE C: convert x -> bf16 frags + x^2 sum (VALU under load latency) ----
    float x2 = 0.f;
    bf16x8 xf[2][2];
#pragma unroll
    for (int t = 0; t < 2; ++t)
#pragma unroll
        for (int f = 0; f < 2; ++f) {
            bf16x8 v;
#pragma unroll
            for (int j = 0; j < 8; ++j) {
                const float xv = xr[t * 16 + f * 8 + j];
                x2 = fmaf(xv, xv, x2);
                v[j] = (short)f32_to_bf16_rne(xv);
            }
            xf[t][f] = v;
        }

    // ---- LDS writes (swizzled dest) ----
#pragma unroll
    for (int r = 0; r < 16; ++r) {
        const int idx = r * 256 + tid;
        const int sw  = (idx & ~7) | ((idx ^ (idx >> 3)) & 7);  // ch ^ (row&7)
        wl16[sw] = sr[r];
    }
    if (tid < 128) ((f32x4*)wwl)[tid] = wws;
    __syncthreads();                               // LDS codebook ready

    // ---- MFMA argmin over 512 codes from LDS ----
    const int   sw0  = (g ^ (c & 7)) << 4;         // loop-invariant swizzle
    const char* arow = smem + c * 128;
    unsigned int best[2] = {0xFFFFFFFFu, 0xFFFFFFFFu};

#pragma unroll 4
    for (int it = 0; it < 32; ++it) {
        const bf16x8 a0  = *(const bf16x8*)(arow + it * 2048 + sw0);
        const bf16x8 a1  = *(const bf16x8*)(arow + it * 2048 + (sw0 ^ 64));
        const f32x4  ww4 = *(const f32x4*)(wwl + it * 16 + g * 4);

        const unsigned int kb = (unsigned int)(it * 16 + g * 4);
#pragma unroll
        for (int t = 0; t < 2; ++t) {
            f32x4 acc = __builtin_amdgcn_mfma_f32_16x16x32_bf16(a0, xf[t][0], ww4, 0, 0, 0);
            acc       = __builtin_amdgcn_mfma_f32_16x16x32_bf16(a1, xf[t][1], acc, 0, 0, 0);
            const unsigned int t0 = (__builtin_bit_cast(unsigned int, acc[0]) & 0xFFFFFE00u) | (kb + 0);
            const unsigned int t1 = (__builtin_bit_cast(unsigned int, acc[1]) & 0xFFFFFE00u) | (kb + 1);
            const unsigned int t2 = (__builtin_bit_cast(unsigned int, acc[2]) & 0xFFFFFE00u) | (kb + 2);
            const unsigned int t3 = (__builtin_bit_cast(unsigned int, acc[3]) & 0xFFFFFE00u) | (kb + 3);
            best[t] = umin32(umin32(umin32(t0, t1), umin32(t2, t3)), best[t]);
        }
    }

    // reduce over the 4 k-groups (lanes c, c+16, c+32, c+48)
#pragma unroll
    for (int t = 0; t < 2; ++t) {
        unsigned int o;
        o = __shfl_xor(best[t], 16); best[t] = umin32(best[t], o);
        o = __shfl_xor(best[t], 32); best[t] = umin32(best[t], o);
    }

    // ---- loss: reduce + single atomic BEFORE stores (drain off critical path) ----
    float ssum = 0.f;
#pragma unroll
    for (int t = 0; t < 2; ++t)
        ssum += __builtin_bit_cast(float, best[t] & 0xFFFFFE00u) - 2.0f;
    float contrib = x2 + 0.25f * ssum;
#pragma unroll
    for (int off = 32; off; off >>= 1) contrib += __shfl_xor(contrib, off, 64);
    __shared__ float wsum[4];
    if (l == 0) wsum[wave] = contrib;
    __syncthreads();
    if (tid == 0) {
        const float tot = (wsum[0] + wsum[1]) + (wsum[2] + wsum[3]);
        atomicAdd(out + TOTAL, tot * (1.25f / (float)TOTAL));
    }

    // ---- write quantized output gathered from the LDS codebook ----
    // q = -0.5 * bf16(-2w): exact *0.5, only bf16(w) rounding (~4e-6).
    const int p4   = (l & 3) * 4;
    const int drow = l >> 2;
#pragma unroll
    for (int t = 0; t < 2; ++t) {
        int k4[4];
#pragma unroll
        for (int j = 0; j < 4; ++j)
            k4[j] = (int)(__shfl(best[t], p4 + j) & 511u);
        float* obase = out + (size_t)b * (DIM * HW) + hw0 + t * 16 + p4;
#pragma unroll
        for (int i = 0; i < 4; ++i) {
            const int d = i * 16 + drow;
            f32x4 q;
#pragma unroll
            for (int j = 0; j < 4; ++j) {
                const int k = k4[j];
                const int byte = k * 128 + ((((d >> 3) ^ (k & 7))) << 4) + ((d & 7) << 1);
                const unsigned short wv = *(const unsigned short*)(smem + byte);
                q[j] = -0.5f * __builtin_bit_cast(float, (unsigned int)wv << 16);
            }
            *(f32x4*)(obase + d * HW) = q;
        }
    }
    // no trailing barrier: stores drain at endpgm
}

extern "C" void kernel_launch(void* const* d_in, const int* in_sizes, int n_in,
                              void* d_out, int out_size, void* d_ws, size_t ws_size,
                              hipStream_t stream) {
    const float* latents = (const float*)d_in[0];
    const float* emb     = (const float*)d_in[1];
    float* out = (float*)d_out;

    unsigned short* wbf = (unsigned short*)d_ws;
    float*          wwb = (float*)((char*)d_ws + 65536);

    static bool attr_done = false;
    if (!attr_done) {
        (void)hipFuncSetAttribute((const void*)fused_vq_kernel,
                                  hipFuncAttributeMaxDynamicSharedMemorySize, 66560);
        attr_done = true;
    }

    prep_kernel<<<128, 256, 0, stream>>>(emb, wbf, wwb, out);
    fused_vq_kernel<<<FUSED_BLOCKS, 256, 66560, stream>>>(latents, wbf, wwb, out);
}

// Round 12
// 26.323 us; speedup vs baseline: 3.5208x; 1.0315x over previous
//
#include <hip/hip_runtime.h>

// VectorQuantizer on MI355X — fused MFMA argmin + quantize + loss, v8.
// latents: [64, 64, 32, 32] f32, embedding: [512, 64] f32.
// d_out: quantized_st [64,64,32,32] f32 (4194304 elems) then vq_loss scalar f32.
// Math: quantized_st == embedding[argmin d2], vq_loss == 1.25 * mean((q - x)^2).
// Identity: per position, (q-x)^2 summed over d = (winning_score - 2) + ||x||^2.
//
// v8 vs v7: 8-wave blocks over 256 consecutive positions; winning indices
// shared via LDS bestk[256]; output store is block-cooperative so each store
// instruction writes 1 KB contiguous (one d-row of 256 floats) instead of
// 16 x 64B scattered segments; 2 blocks/CU * 8 waves = 16 waves/CU.
// Kept: LDS XOR-swizzled bf16 codebook, packed u32 argmin, batched loads,
// one f32 atomic per block, no threadfence, no nontemporal.

#define NUM_EMB 512
#define DIM 64
#define HW 1024
#define TOTAL 4194304
#define FUSED_BLOCKS 256    // 512 threads = 8 waves; 256 positions per block

typedef __attribute__((ext_vector_type(8))) short bf16x8;
typedef __attribute__((ext_vector_type(4))) float f32x4;
typedef __attribute__((ext_vector_type(4))) unsigned short u16x4;

// d_ws layout:
//   [0, 65536)        : ushort wbf[512*64]   (bf16 bits of -2*W)
//   [65536, 67584)    : float  wwb[512]      (||w||^2 + 2.0 bias)

__device__ __forceinline__ unsigned short f32_to_bf16_rne(float f) {
    unsigned int b = __builtin_bit_cast(unsigned int, f);
    return (unsigned short)((b + 0x7FFFu + ((b >> 16) & 1u)) >> 16);
}

__device__ __forceinline__ unsigned int umin32(unsigned int a, unsigned int b) {
    return a < b ? a : b;
}

__global__ __launch_bounds__(256) void prep_kernel(
    const float* __restrict__ emb, unsigned short* __restrict__ wbf,
    float* __restrict__ wwb, float* __restrict__ out) {
    const int t = blockIdx.x * 256 + threadIdx.x;  // 32768 threads
    if (t == 0) out[TOTAL] = 0.f;                  // loss accumulator
    if (t < NUM_EMB * DIM) wbf[t] = f32_to_bf16_rne(-2.0f * emb[t]);
    if (t < NUM_EMB) {
        const float* row = emb + t * DIM;
        float s = 0.f;
#pragma unroll
        for (int i = 0; i < DIM; ++i) s = fmaf(row[i], row[i], s);
        wwb[t] = s + 2.0f;                         // +2 bias keeps packed scores positive
    }
}

// LDS: [0,65536) swizzled codebook, [65536,67584) wwl, [67584,68096) bestk u16,
// [68096,68128) wsum f32[8].  Swizzle: 16B chunk ch of row k at chunk ch^(k&7).
// Wave lane l: c=l&15 (position in 16-tile), g=l>>4 (k-group / dim-block).
// acc[r] = ||w_k||^2 + 2 - 2 x.w_k for k = k0+g*4+r.  Packed argmin:
// u32 = (score_bits & ~511) | k; running min_u32; strict-min keeps smallest k
// on masked-score ties (jnp.argmin tie-break).
__global__ __launch_bounds__(512, 4) void fused_vq_kernel(
    const float* __restrict__ latents, const unsigned short* __restrict__ wbf,
    const float* __restrict__ wwb, float* __restrict__ out) {
    extern __shared__ char smem[];                 // 68128 B dynamic
    f32x4* wl16 = (f32x4*)smem;                    // 4096 x 16B (swizzled wbf)
    float* wwl  = (float*)(smem + 65536);          // 512 floats
    unsigned short* bestk = (unsigned short*)(smem + 67584);  // 256 u16
    float* wsum = (float*)(smem + 68096);          // 8 floats

    const int tid  = threadIdx.x;
    const int wave = tid >> 6;                     // 0..7
    const int l    = tid & 63;
    const int c    = l & 15;
    const int g    = l >> 4;

    const int n0  = blockIdx.x * 256;              // 256 positions, same b
    const int b   = n0 >> 10;
    const int hw0 = n0 & 1023;
    const int pw  = wave * 32;                     // wave's 32-pos strip
    const float* xbase = latents + (size_t)b * (DIM * HW) + hw0 + pw + c;

    // ---- PHASE A: issue ALL 32 x-loads as one batch ----
    float xr[32];
#pragma unroll
    for (int t = 0; t < 2; ++t)
#pragma unroll
        for (int f = 0; f < 2; ++f)
#pragma unroll
            for (int j = 0; j < 8; ++j)
                xr[t * 16 + f * 8 + j] = xbase[(f * 32 + g * 8 + j) * HW + t * 16];

    // ---- PHASE B: issue ALL staging loads (8 chunks/thread) ----
    const f32x4* wg = (const f32x4*)wbf;           // 4096 chunks of 16B
    f32x4 sr[8];
#pragma unroll
    for (int r = 0; r < 8; ++r) sr[r] = wg[r * 512 + tid];
    f32x4 wws;
    if (tid < 128) wws = ((const f32x4*)wwb)[tid];

    // ---- PHASE C: convert x -> bf16 frags + x^2 (4 chains) ----
    float x2a = 0.f, x2b = 0.f, x2c = 0.f, x2d = 0.f;
    bf16x8 xf[2][2];
#pragma unroll
    for (int t = 0; t < 2; ++t)
#pragma unroll
        for (int f = 0; f < 2; ++f) {
            bf16x8 v;
#pragma unroll
            for (int j = 0; j < 8; ++j) {
                const float xv = xr[t * 16 + f * 8 + j];
                if (j < 2)      x2a = fmaf(xv, xv, x2a);
                else if (j < 4) x2b = fmaf(xv, xv, x2b);
                else if (j < 6) x2c = fmaf(xv, xv, x2c);
                else            x2d = fmaf(xv, xv, x2d);
                v[j] = (short)f32_to_bf16_rne(xv);
            }
            xf[t][f] = v;
        }
    const float x2 = (x2a + x2b) + (x2c + x2d);

    // ---- LDS writes (swizzled dest) ----
#pragma unroll
    for (int r = 0; r < 8; ++r) {
        const int idx = r * 512 + tid;
        const int sw  = (idx & ~7) | ((idx ^ (idx >> 3)) & 7);  // ch ^ (row&7)
        wl16[sw] = sr[r];
    }
    if (tid < 128) ((f32x4*)wwl)[tid] = wws;
    __syncthreads();                               // LDS codebook ready

    // ---- MFMA argmin over 512 codes from LDS ----
    const int   sw0  = (g ^ (c & 7)) << 4;         // loop-invariant swizzle
    const char* arow = smem + c * 128;
    unsigned int best[2] = {0xFFFFFFFFu, 0xFFFFFFFFu};

#pragma unroll 4
    for (int it = 0; it < 32; ++it) {
        const bf16x8 a0  = *(const bf16x8*)(arow + it * 2048 + sw0);
        const bf16x8 a1  = *(const bf16x8*)(arow + it * 2048 + (sw0 ^ 64));
        const f32x4  ww4 = *(const f32x4*)(wwl + it * 16 + g * 4);

        const unsigned int kb = (unsigned int)(it * 16 + g * 4);
#pragma unroll
        for (int t = 0; t < 2; ++t) {
            f32x4 acc = __builtin_amdgcn_mfma_f32_16x16x32_bf16(a0, xf[t][0], ww4, 0, 0, 0);
            acc       = __builtin_amdgcn_mfma_f32_16x16x32_bf16(a1, xf[t][1], acc, 0, 0, 0);
            const unsigned int t0 = (__builtin_bit_cast(unsigned int, acc[0]) & 0xFFFFFE00u) | (kb + 0);
            const unsigned int t1 = (__builtin_bit_cast(unsigned int, acc[1]) & 0xFFFFFE00u) | (kb + 1);
            const unsigned int t2 = (__builtin_bit_cast(unsigned int, acc[2]) & 0xFFFFFE00u) | (kb + 2);
            const unsigned int t3 = (__builtin_bit_cast(unsigned int, acc[3]) & 0xFFFFFE00u) | (kb + 3);
            best[t] = umin32(umin32(umin32(t0, t1), umin32(t2, t3)), best[t]);
        }
    }

    // reduce over the 4 k-groups (lanes c, c+16, c+32, c+48)
#pragma unroll
    for (int t = 0; t < 2; ++t) {
        unsigned int o;
        o = __shfl_xor(best[t], 16); best[t] = umin32(best[t], o);
        o = __shfl_xor(best[t], 32); best[t] = umin32(best[t], o);
    }

    // ---- loss partial + publish winning k's ----
    float ssum = 0.f;
#pragma unroll
    for (int t = 0; t < 2; ++t)
        ssum += __builtin_bit_cast(float, best[t] & 0xFFFFFE00u) - 2.0f;
    float contrib = x2 + 0.25f * ssum;             // scores replicated x4 over g
#pragma unroll
    for (int off = 32; off; off >>= 1) contrib += __shfl_xor(contrib, off, 64);
    if (l == 0) wsum[wave] = contrib;
    if (l < 16) {
        bestk[pw + l]      = (unsigned short)(best[0] & 511u);
        bestk[pw + 16 + l] = (unsigned short)(best[1] & 511u);
    }
    __syncthreads();                               // bestk + wsum ready

    if (tid == 0) {
        float tot = 0.f;
#pragma unroll
        for (int i = 0; i < 8; ++i) tot += wsum[i];
        atomicAdd(out + TOTAL, tot * (1.25f / (float)TOTAL));
    }

    // ---- block-cooperative coalesced store: one d-row (256 floats = 1 KB)
    //      per wave-instruction; q = -0.5 * bf16(-2w) gathered from LDS ----
    float* obase = out + (size_t)b * (DIM * HW) + hw0;
#pragma unroll
    for (int i = 0; i < 8; ++i) {
        const int e0 = i * 2048 + tid * 4;         // element in [256 pos x 64 d]
        const int d  = e0 >> 8;
        const int p  = e0 & 255;
        const u16x4 k4 = *(const u16x4*)(bestk + p);
        f32x4 q;
#pragma unroll
        for (int j = 0; j < 4; ++j) {
            const int k = (int)k4[j];
            const int byte = k * 128 + (((d >> 3) ^ (k & 7)) << 4) + ((d & 7) << 1);
            const unsigned short wv = *(const unsigned short*)(smem + byte);
            q[j] = -0.5f * __builtin_bit_cast(float, (unsigned int)wv << 16);
        }
        *(f32x4*)(obase + d * HW + p) = q;
    }
    // no trailing barrier: stores drain at endpgm
}

extern "C" void kernel_launch(void* const* d_in, const int* in_sizes, int n_in,
                              void* d_out, int out_size, void* d_ws, size_t ws_size,
                              hipStream_t stream) {
    const float* latents = (const float*)d_in[0];
    const float* emb     = (const float*)d_in[1];
    float* out = (float*)d_out;

    unsigned short* wbf = (unsigned short*)d_ws;
    float*          wwb = (float*)((char*)d_ws + 65536);

    static bool attr_done = false;
    if (!attr_done) {
        (void)hipFuncSetAttribute((const void*)fused_vq_kernel,
                                  hipFuncAttributeMaxDynamicSharedMemorySize, 68128);
        attr_done = true;
    }

    prep_kernel<<<128, 256, 0, stream>>>(emb, wbf, wwb, out);
    fused_vq_kernel<<<FUSED_BLOCKS, 512, 68128, stream>>>(latents, wbf, wwb, out);
}